// Round 10
// baseline (232.676 us; speedup 1.0000x reference)
//
#include <hip/hip_runtime.h>

// WeatherLSTM round 10: R9's decoupled producer/consumer sync x 4 waves/SIMD.
//  - grid 256 x 1024 thr (16 waves): waves 0-7 = group A (layer 0), waves
//    8-15 = group B (layer 1, lag up to 8). Each SIMD hosts 2 A + 2 B waves
//    drifting freely -> 4 independent instruction streams to fill the
//    ~740 cyc/iter dual-stall idle measured across R3-R9 (30% of 2436).
//  - Wave owns 8 units as 2 M-tiles (R4 mapping: tile T unit = ub+2*quad+T,
//    packed b32 h-writes). Per-SIMD totals conserved: 28 MFMA, 56 trans.
//  - Sync (R9 scheme, group stride 8): aCnt/bCnt = 8*steps done.
//      A@k: aCnt>=8k; k>=8: bCnt>=8(k-7) (ring slot free). Batched polls.
//      B@k: bCnt>=8k; aCnt>=8(k+1) (h0(k) ready).
//    A strictly ahead -> deadlock-free; 1 block/CU, all waves co-resident.
//  - h0: 8-slot ring; h1: 2 slots; ROWB=208 f16 rows; x table in LDS.
//  - Acts: hardware v_exp/v_rcp (R7: polys worse), weights prescaled
//    log2e / 2log2e, shared-rcp + fused i*tanh(g).
//  - MFMA layouts per m89/m91/m120 (verified R2-R9: absmax 4.8828e-4).

typedef _Float16 h8 __attribute__((ext_vector_type(8)));
typedef _Float16 h4 __attribute__((ext_vector_type(4)));
typedef float f4 __attribute__((ext_vector_type(4)));

#define ROWB 208
#define HBUF (16 * ROWB)            // 3328 B per h slot
#define XTAB_OFF 0
#define XTAB_BYTES (168 * 256)      // 43008 B
#define H0_OFF XTAB_BYTES           // 8-slot ring
#define H1_OFF (H0_OFF + 8 * HBUF)  // 2 slots
#define CNT_OFF (H1_OFF + 2 * HBUF)
#define SMEM_TOTAL (CNT_OFF + 128)  // 76416 B

#define K1F 1.4426950408889634f     // log2(e)
#define K2F 2.8853900817779268f     // 2*log2(e)

__device__ __forceinline__ float exp2_(float x) {
#if __has_builtin(__builtin_amdgcn_exp2f)
  return __builtin_amdgcn_exp2f(x);
#else
  float r; asm("v_exp_f32 %0, %1" : "=v"(r) : "v"(x)); return r;
#endif
}
__device__ __forceinline__ float rcp_(float x) {
#if __has_builtin(__builtin_amdgcn_rcpf)
  return __builtin_amdgcn_rcpf(x);
#else
  float r; asm("v_rcp_f32 %0, %1" : "=v"(r) : "v"(x)); return r;
#endif
}

__device__ __forceinline__ f4 mfma16(h8 a, h8 b, f4 c) {
  return __builtin_amdgcn_mfma_f32_16x16x32_f16(a, b, c, 0, 0, 0);
}

__device__ __forceinline__ h8 load_w8s(const float* __restrict__ p, float sc) {
  h8 r;
#pragma unroll
  for (int j = 0; j < 8; j++) r[j] = (_Float16)(p[j] * sc);
  return r;
}

__device__ __forceinline__ unsigned packh2(float a, float b) {
  unsigned lo = (unsigned)__builtin_bit_cast(unsigned short, (_Float16)a);
  unsigned hi = (unsigned)__builtin_bit_cast(unsigned short, (_Float16)b);
  return lo | (hi << 16);
}

// a[0]=i,a[1]=f,a[3]=o prescaled K1F; a[2]=g prescaled K2F.
__device__ __forceinline__ void lstm_act(f4 a, float& c, float& h) {
  float Ei = exp2_(-a[0]);
  float Ef = exp2_(-a[1]);
  float Eg = exp2_(a[2]);
  float Eo = exp2_(-a[3]);
  float A = 1.f + Ei, B = 1.f + Ef, C = 1.f + Eg, D = 1.f + Eo;
  float AB = A * B, CD = C * D, BD = B * D;
  float R  = rcp_(AB * CD);
  float fv = (A * CD) * R;               // sigm(f)
  float ig = (BD * (Eg - 1.f)) * R;      // sigm(i)*tanh(g)
  float ov = (AB * C) * R;               // sigm(o)
  c = fmaf(fv, c, ig);
  float r2 = rcp_(exp2_(c * K2F) + 1.f);
  h = ov * fmaf(-2.f, r2, 1.f);
}

__device__ __forceinline__ int ld_cnt(int* p) {
  return __hip_atomic_load(p, __ATOMIC_ACQUIRE, __HIP_MEMORY_SCOPE_WORKGROUP);
}
__device__ __forceinline__ void arrive(int* p, int lane) {
  if (lane == 0)
    __hip_atomic_fetch_add(p, 1, __ATOMIC_RELEASE, __HIP_MEMORY_SCOPE_WORKGROUP);
}

extern "C" __global__ void __launch_bounds__(1024, 4)
weather_lstm_mfma10(const float* __restrict__ x,
                    const float* __restrict__ Wih0, const float* __restrict__ Whh0,
                    const float* __restrict__ bih0, const float* __restrict__ bhh0,
                    const float* __restrict__ Wih1, const float* __restrict__ Whh1,
                    const float* __restrict__ bih1, const float* __restrict__ bhh1,
                    const float* __restrict__ W1, const float* __restrict__ b1,
                    const float* __restrict__ W2, const float* __restrict__ b2,
                    float* __restrict__ out)
{
  __shared__ __align__(16) unsigned char smem[SMEM_TOTAL];
  const int tid  = threadIdx.x;
  const int lane = tid & 63;
  const int w    = tid >> 6;      // wave 0..15
  const int col  = lane & 15;     // sample index (B-frag n / C col)
  const int quad = lane >> 4;     // 0..3
  const int sB   = blockIdx.x * 16;
  const bool isA = (w < 8);
  const int gw   = w & 7;         // wave index within group
  const int ub   = gw * 8;        // unit base (8 units per wave)

  const int g_  = col & 3;
  const int ul_ = col >> 2;
  const float asc = (g_ == 2) ? K2F : K1F;

  int* aCnt = (int*)(smem + CNT_OFF);
  int* bCnt = (int*)(smem + CNT_OFF + 64);

  // ---- zero LDS, build x table (all waves) ----
  for (int idx = tid; idx < SMEM_TOTAL / 4; idx += 1024) ((int*)smem)[idx] = 0;
  __syncthreads();
  for (int idx = tid; idx < 16 * 168; idx += 1024) {
    const int c_ = idx / 168, t_ = idx - c_ * 168;
    f4 xv = *(const f4*)(x + ((size_t)(sB + c_) * 168 + t_) * 4);
    h4 xh;
#pragma unroll
    for (int j = 0; j < 4; j++) xh[j] = (_Float16)xv[j];
    *(h4*)(smem + XTAB_OFF + t_ * 256 + c_ * 16) = xh;
  }
  __syncthreads();

  const int bo  = col * ROWB + quad * 16;              // B-frag byte offset
  const int wo  = col * ROWB + (ub + 2 * quad) * 2;    // packed h-write offset
  float hl[2] = {0.f, 0.f};

  if (isA) {
    // ================= group A: layer 0 =================
    h8 a0[2][3];
    f4 bias0v[2];
#pragma unroll
    for (int T = 0; T < 2; T++) {
      const int r = g_ * 64 + ub + 2 * ul_ + T;
#pragma unroll
      for (int f = 0; f < 2; f++)
        a0[T][f] = load_w8s(Whh0 + r * 64 + f * 32 + quad * 8, asc);
      h8 xw = {};
      if (quad == 0) {
#pragma unroll
        for (int j = 0; j < 4; j++) xw[j] = (_Float16)(Wih0[r * 4 + j] * asc);
      }
      a0[T][2] = xw;
#pragma unroll
      for (int reg = 0; reg < 4; reg++) {
        const int rb = reg * 64 + ub + 2 * quad + T;
        const float bs = (reg == 2) ? K2F : K1F;
        bias0v[T][reg] = (bih0[rb] + bhh0[rb]) * bs;
      }
    }
    const unsigned char* xp = smem + XTAB_OFF + col * 16;
    float c0[2] = {0.f, 0.f};
    int safeA = 0;

    for (int k = 0; k < 168; k++) {
      while (k >= safeA) {                      // batched poll
        int lim = (ld_cnt(aCnt) >> 3) + 1;      // siblings wrote h0(k-1)
        if (k >= 8) {
          int lim2 = (ld_cnt(bCnt) >> 3) + 8;   // ring slot k&7 free
          lim = lim < lim2 ? lim : lim2;
        }
        safeA = lim;
      }
      const unsigned char* h0r = smem + H0_OFF + ((k + 7) & 7) * HBUF;
      unsigned char*       h0w = smem + H0_OFF + (k & 7) * HBUF;

      h8 b0  = *(const h8*)(h0r + bo);
      h8 b1v = *(const h8*)(h0r + bo + 64);
      h8 bx  = *(const h8*)(xp + k * 256);

      f4 A0 = mfma16(a0[0][0], b0, bias0v[0]);
      f4 A1 = mfma16(a0[1][0], b0, bias0v[1]);
      A0 = mfma16(a0[0][1], b1v, A0);
      A1 = mfma16(a0[1][1], b1v, A1);
      A0 = mfma16(a0[0][2], bx, A0);
      A1 = mfma16(a0[1][2], bx, A1);

      float h0o[2];
      lstm_act(A0, c0[0], h0o[0]);
      lstm_act(A1, c0[1], h0o[1]);
      *(unsigned*)(h0w + wo) = packh2(h0o[0], h0o[1]);
      arrive(aCnt, lane);
    }
  } else {
    // ================= group B: layer 1 (lag up to 8) =================
    h8 a1i[2][2], a1h[2][2];
    f4 bias1v[2];
#pragma unroll
    for (int T = 0; T < 2; T++) {
      const int r = g_ * 64 + ub + 2 * ul_ + T;
#pragma unroll
      for (int f = 0; f < 2; f++) {
        a1i[T][f] = load_w8s(Wih1 + r * 64 + f * 32 + quad * 8, asc);
        a1h[T][f] = load_w8s(Whh1 + r * 64 + f * 32 + quad * 8, asc);
      }
#pragma unroll
      for (int reg = 0; reg < 4; reg++) {
        const int rb = reg * 64 + ub + 2 * quad + T;
        const float bs = (reg == 2) ? K2F : K1F;
        bias1v[T][reg] = (bih1[rb] + bhh1[rb]) * bs;
      }
    }
    float c1[2] = {0.f, 0.f};
    int safeB = 0;

    for (int k = 0; k < 168; k++) {
      while (k >= safeB) {                      // batched poll
        int limO = (ld_cnt(bCnt) >> 3) + 1;     // siblings wrote h1(k-1)
        int limA = (ld_cnt(aCnt) >> 3);         // h0(k) ready: aCnt>=8(k+1)
        safeB = limO < limA ? limO : limA;
      }
      const unsigned char* hp = smem + H0_OFF + (k & 7) * HBUF;        // h0(k)
      const unsigned char* hq = smem + H1_OFF + ((k + 1) & 1) * HBUF;  // h1(k-1)
      unsigned char*       h1w = smem + H1_OFF + (k & 1) * HBUF;       // h1(k)

      h8 p0 = *(const h8*)(hp + bo);
      h8 p1 = *(const h8*)(hp + bo + 64);
      h8 q0 = *(const h8*)(hq + bo);
      h8 q1 = *(const h8*)(hq + bo + 64);

      f4 C0 = mfma16(a1i[0][0], p0, bias1v[0]);
      f4 C1 = mfma16(a1i[1][0], p0, bias1v[1]);
      C0 = mfma16(a1i[0][1], p1, C0);
      C1 = mfma16(a1i[1][1], p1, C1);
      C0 = mfma16(a1h[0][0], q0, C0);
      C1 = mfma16(a1h[1][0], q0, C1);
      C0 = mfma16(a1h[0][1], q1, C0);
      C1 = mfma16(a1h[1][1], q1, C1);

      lstm_act(C0, c1[0], hl[0]);
      lstm_act(C1, c1[1], hl[1]);
      *(unsigned*)(h1w + wo) = packh2(hl[0], hl[1]);
      arrive(bCnt, lane);
    }
  }
  __syncthreads();

  // ---------- MLP head (x table region dead; overlay) ----------
  float* fh = (float*)smem;              // [16][64] final h2, fp32
  if (!isA) {
#pragma unroll
    for (int T = 0; T < 2; T++)
      fh[col * 64 + (ub + 2 * quad + T)] = hl[T];
  }
  __syncthreads();

  {
    const int u = tid & 63, grp = tid >> 6;  // 16 grps x 1 sample
    float za = b1[u];
    const float* w1r = W1 + u * 64;
    const float* f0 = fh + grp * 64;
    for (int j = 0; j < 64; j++) za += w1r[j] * f0[j];
    float* zl = (float*)(smem + 8192);     // [16][64]
    zl[grp * 64 + u] = fmaxf(za, 0.f);
  }
  __syncthreads();

  if (tid < 192) {
    const float* zl = (const float*)(smem + 8192);
    const int s = tid / 12, o = tid - s * 12;
    float a = b2[o];
    for (int j = 0; j < 64; j++) a += W2[o * 64 + j] * zl[s * 64 + j];
    out[(sB + s) * 12 + o] = a;
  }
}

extern "C" void kernel_launch(void* const* d_in, const int* in_sizes, int n_in,
                              void* d_out, int out_size, void* d_ws, size_t ws_size,
                              hipStream_t stream) {
  (void)in_sizes; (void)n_in; (void)d_ws; (void)ws_size; (void)out_size;
  const float* x    = (const float*)d_in[0];
  const float* Wih0 = (const float*)d_in[1];
  const float* Whh0 = (const float*)d_in[2];
  const float* bih0 = (const float*)d_in[3];
  const float* bhh0 = (const float*)d_in[4];
  const float* Wih1 = (const float*)d_in[5];
  const float* Whh1 = (const float*)d_in[6];
  const float* bih1 = (const float*)d_in[7];
  const float* bhh1 = (const float*)d_in[8];
  const float* W1   = (const float*)d_in[9];
  const float* b1   = (const float*)d_in[10];
  const float* W2   = (const float*)d_in[11];
  const float* b2   = (const float*)d_in[12];

  weather_lstm_mfma10<<<dim3(256), dim3(1024), 0, stream>>>(
      x, Wih0, Whh0, bih0, bhh0, Wih1, Whh1, bih1, bhh1, W1, b1, W2, b2,
      (float*)d_out);
}